// Round 1
// baseline (6396.656 us; speedup 1.0000x reference)
//
#include <hip/hip_runtime.h>
#include <stdint.h>

#define T_STEPS 128
#define BATCH   512
#define OBSD    1024
#define HD      512
#define FCD     512
#define MROWS   (T_STEPS * BATCH)   // 65536

typedef unsigned short ushort_t;
typedef __attribute__((ext_vector_type(8))) short bf16x8;
typedef __attribute__((ext_vector_type(4))) float f32x4;

__device__ inline ushort_t f2bf(float f) {
    union { float f; uint32_t u; } v; v.f = f;
    uint32_t r = v.u + 0x7FFFu + ((v.u >> 16) & 1u);
    return (ushort_t)(r >> 16);
}
__device__ inline float bf2f(ushort_t h) {
    union { uint32_t u; float f; } v; v.u = ((uint32_t)h) << 16;
    return v.f;
}
__device__ inline float fsigmoid(float x) {
    x = fminf(fmaxf(x, -30.f), 30.f);
    return 1.f / (1.f + __expf(-x));
}
__device__ inline float ftanh(float x) {
    float e = __expf(fminf(fmaxf(2.f * x, -30.f), 30.f));
    return (e - 1.f) / (e + 1.f);
}

// ---------------- weight prep: fp32 [R,C] -> bf16 [C,R] ----------------
__global__ void transpose_to_bf16(const float* __restrict__ in,
                                  ushort_t* __restrict__ out, int R, int C) {
    __shared__ float tile[32][33];
    int tx = threadIdx.x, ty = threadIdx.y;
    int c0 = blockIdx.x * 32, r0 = blockIdx.y * 32;
    for (int yy = 0; yy < 4; ++yy)
        tile[ty + 8 * yy][tx] = in[(size_t)(r0 + ty + 8 * yy) * C + c0 + tx];
    __syncthreads();
    for (int yy = 0; yy < 4; ++yy)
        out[(size_t)(c0 + ty + 8 * yy) * R + r0 + tx] = f2bf(tile[tx][ty + 8 * yy]);
}

__global__ void init_value(float* __restrict__ v, const float* __restrict__ bc2) {
    int i = blockIdx.x * blockDim.x + threadIdx.x;
    if (i < MROWS) v[i] = bc2[0];
}

// ---------------- generic 64x64 MFMA GEMM: C = A @ B (+epilogues) --------
// A: [M,K] (fp32 if AF32 else bf16), BT: [N,K] bf16 (pre-transposed)
// EPI 0: bias+relu -> bf16 out ; EPI 1: bias -> bf16 out ;
// EPI 2: relu(bias) dot wc2 -> atomicAdd into value[M]
template <int K, int EPI, bool AF32>
__global__ __launch_bounds__(256) void gemm64(
    const void* __restrict__ Aptr, const ushort_t* __restrict__ BT,
    const float* __restrict__ bias, ushort_t* __restrict__ Cout, int ldc,
    const float* __restrict__ wc2, float* __restrict__ value) {
    __shared__ __align__(16) ushort_t Als[64][40];
    __shared__ __align__(16) ushort_t Bls[64][40];
    int tid = threadIdx.x;
    int wave = tid >> 6, lane = tid & 63, quad = lane >> 4, l16 = lane & 15;
    int bm = blockIdx.x * 64, bn = blockIdx.y * 64;
    int lrow = tid >> 2, lk = (tid & 3) * 8;

    f32x4 acc[4];
    for (int c = 0; c < 4; ++c) acc[c] = (f32x4){0.f, 0.f, 0.f, 0.f};

    for (int k0 = 0; k0 < K; k0 += 32) {
        if constexpr (AF32) {
            const float* A = (const float*)Aptr;
            const float4* pa =
                (const float4*)&A[(size_t)(bm + lrow) * K + k0 + lk];
            float4 a0 = pa[0], a1 = pa[1];
            ushort_t* d = &Als[lrow][lk];
            d[0] = f2bf(a0.x); d[1] = f2bf(a0.y); d[2] = f2bf(a0.z); d[3] = f2bf(a0.w);
            d[4] = f2bf(a1.x); d[5] = f2bf(a1.y); d[6] = f2bf(a1.z); d[7] = f2bf(a1.w);
        } else {
            const ushort_t* A = (const ushort_t*)Aptr;
            *(bf16x8*)&Als[lrow][lk] =
                *(const bf16x8*)&A[(size_t)(bm + lrow) * K + k0 + lk];
        }
        *(bf16x8*)&Bls[lrow][lk] =
            *(const bf16x8*)&BT[(size_t)(bn + lrow) * K + k0 + lk];
        __syncthreads();
        bf16x8 a = *(const bf16x8*)&Als[16 * wave + l16][quad * 8];
        for (int c = 0; c < 4; ++c) {
            bf16x8 b = *(const bf16x8*)&Bls[16 * c + l16][quad * 8];
            acc[c] = __builtin_amdgcn_mfma_f32_16x16x32_bf16(a, b, acc[c], 0, 0, 0);
        }
        __syncthreads();
    }

    int row_l = 16 * wave + 4 * quad;
    if constexpr (EPI == 0 || EPI == 1) {
        for (int c = 0; c < 4; ++c) {
            int col = bn + 16 * c + l16;
            float bv = bias[col];
            for (int i = 0; i < 4; ++i) {
                float v = acc[c][i] + bv;
                if constexpr (EPI == 0) v = fmaxf(v, 0.f);
                Cout[(size_t)(bm + row_l + i) * ldc + col] = f2bf(v);
            }
        }
    } else {
        float s[4] = {0.f, 0.f, 0.f, 0.f};
        for (int c = 0; c < 4; ++c) {
            int col = bn + 16 * c + l16;
            float bv = bias[col], w2 = wc2[col];
            for (int i = 0; i < 4; ++i)
                s[i] += fmaxf(acc[c][i] + bv, 0.f) * w2;
        }
        for (int i = 0; i < 4; ++i) {
            float v = s[i];
            v += __shfl_xor(v, 1);
            v += __shfl_xor(v, 2);
            v += __shfl_xor(v, 4);
            v += __shfl_xor(v, 8);
            if (l16 == 0) atomicAdd(&value[bm + row_l + i], v);
        }
    }
}

// ---------------- rowwise LayerNorm over H=512, in-place on bf16 --------
__global__ __launch_bounds__(256) void ln_kernel(ushort_t* __restrict__ emb,
                                                 const float* __restrict__ scale,
                                                 const float* __restrict__ biasv) {
    int wave = threadIdx.x >> 6, lane = threadIdx.x & 63;
    size_t row = (size_t)blockIdx.x * 4 + wave;
    ushort_t* p = &emb[row * HD + lane * 8];
    bf16x8 xv = *(const bf16x8*)p;
    float x[8];
    float sum = 0.f, sq = 0.f;
    for (int j = 0; j < 8; ++j) {
        x[j] = bf2f((ushort_t)xv[j]);
        sum += x[j];
        sq += x[j] * x[j];
    }
    for (int off = 32; off > 0; off >>= 1) {
        sum += __shfl_xor(sum, off);
        sq += __shfl_xor(sq, off);
    }
    float mean = sum * (1.f / 512.f);
    float var = fmaxf(sq * (1.f / 512.f) - mean * mean, 0.f);
    float inv = rsqrtf(var + 1e-6f);
    bf16x8 ov;
    for (int j = 0; j < 8; ++j) {
        int col = lane * 8 + j;
        ov[j] = (short)f2bf((x[j] - mean) * inv * scale[col] + biasv[col]);
    }
    *(bf16x8*)p = ov;
}

// ---------------- GRU scan: 32 blocks, each owns 16 batch rows ----------
__global__ __launch_bounds__(1024) void scan_kernel(
    const float* __restrict__ hidden, const int* __restrict__ dones,
    const ushort_t* __restrict__ WhT, const float* __restrict__ bhn,
    const ushort_t* __restrict__ xproj, ushort_t* __restrict__ ys,
    float* __restrict__ hlast) {
    __shared__ __align__(16) ushort_t hls[16][520];
    int tid = threadIdx.x;
    int wave = tid >> 6, lane = tid & 63, quad = lane >> 4, l16 = lane & 15;
    int b0 = blockIdx.x * 16;
    int colbase = 32 * wave;

    float hreg[2][4];
    for (int jj = 0; jj < 2; ++jj) {
        int col = colbase + 16 * jj + l16;
        for (int i = 0; i < 4; ++i)
            hreg[jj][i] = hidden[(size_t)(b0 + 4 * quad + i) * HD + col];
    }

    for (int t = 0; t < T_STEPS; ++t) {
        // reset carry on done (before gates AND before h@Wh)
        for (int i = 0; i < 4; ++i) {
            int done = dones[(size_t)t * BATCH + b0 + 4 * quad + i];
            if (done) { hreg[0][i] = 0.f; hreg[1][i] = 0.f; }
        }
        for (int jj = 0; jj < 2; ++jj) {
            int col = colbase + 16 * jj + l16;
            for (int i = 0; i < 4; ++i)
                hls[4 * quad + i][col] = f2bf(hreg[jj][i]);
        }
        __syncthreads();

        f32x4 accR[2], accZ[2], accN[2];
        for (int jj = 0; jj < 2; ++jj) {
            accR[jj] = (f32x4){0.f, 0.f, 0.f, 0.f};
            accZ[jj] = (f32x4){0.f, 0.f, 0.f, 0.f};
            accN[jj] = (f32x4){0.f, 0.f, 0.f, 0.f};
        }
        for (int kt = 0; kt < 16; ++kt) {
            int k0 = kt * 32;
            bf16x8 a = *(const bf16x8*)&hls[l16][k0 + quad * 8];
            for (int jj = 0; jj < 2; ++jj) {
                int tj = 2 * wave + jj;  // j-tile in [0,32)
                const ushort_t* bp =
                    &WhT[(size_t)(tj * 16 + l16) * HD + k0 + quad * 8];
                bf16x8 bR = *(const bf16x8*)bp;
                bf16x8 bZ = *(const bf16x8*)(bp + 512 * HD);
                bf16x8 bN = *(const bf16x8*)(bp + 1024 * HD);
                accR[jj] = __builtin_amdgcn_mfma_f32_16x16x32_bf16(a, bR, accR[jj], 0, 0, 0);
                accZ[jj] = __builtin_amdgcn_mfma_f32_16x16x32_bf16(a, bZ, accZ[jj], 0, 0, 0);
                accN[jj] = __builtin_amdgcn_mfma_f32_16x16x32_bf16(a, bN, accN[jj], 0, 0, 0);
            }
        }
        __syncthreads();  // all hls reads done before next iter's writes

        for (int jj = 0; jj < 2; ++jj) {
            int col = colbase + 16 * jj + l16;
            float bhnv = bhn[col];
            for (int i = 0; i < 4; ++i) {
                size_t m = (size_t)t * BATCH + b0 + 4 * quad + i;
                const ushort_t* xp = &xproj[m * 1536 + col];
                float xr = bf2f(xp[0]);
                float xz = bf2f(xp[512]);
                float xn = bf2f(xp[1024]);
                float r = fsigmoid(xr + accR[jj][i]);
                float z = fsigmoid(xz + accZ[jj][i]);
                float n = ftanh(xn + r * (accN[jj][i] + bhnv));
                float hnew = (1.f - z) * n + z * hreg[jj][i];
                hreg[jj][i] = hnew;
                ys[m * HD + col] = f2bf(hnew);
            }
        }
    }

    for (int jj = 0; jj < 2; ++jj) {
        int col = colbase + 16 * jj + l16;
        for (int i = 0; i < 4; ++i)
            hlast[(size_t)(b0 + 4 * quad + i) * HD + col] = hreg[jj][i];
    }
}

extern "C" void kernel_launch(void* const* d_in, const int* in_sizes, int n_in,
                              void* d_out, int out_size, void* d_ws,
                              size_t ws_size, hipStream_t stream) {
    const float* hidden      = (const float*)d_in[0];
    const float* world_state = (const float*)d_in[1];
    const int*   dones       = (const int*)d_in[2];
    const float* Wd  = (const float*)d_in[3];
    const float* bd  = (const float*)d_in[4];
    const float* lns = (const float*)d_in[5];
    const float* lnb = (const float*)d_in[6];
    const float* Wi  = (const float*)d_in[7];
    const float* bi  = (const float*)d_in[8];
    const float* Wh  = (const float*)d_in[9];
    const float* bhn = (const float*)d_in[10];
    const float* Wc1 = (const float*)d_in[11];
    const float* bc1 = (const float*)d_in[12];
    const float* Wc2 = (const float*)d_in[13];
    const float* bc2 = (const float*)d_in[14];

    float* out_h = (float*)d_out;            // h_last [512,512]
    float* out_v = out_h + BATCH * HD;       // value  [128,512]

    char* ws = (char*)d_ws;
    ushort_t* WdT   = (ushort_t*)(ws + 0);                    // [512][1024]
    ushort_t* WiT   = (ushort_t*)(ws + 1048576);              // [1536][512]
    ushort_t* WhT   = (ushort_t*)(ws + 2621440);              // [1536][512]
    ushort_t* Wc1T  = (ushort_t*)(ws + 4194304);              // [512][512]
    ushort_t* xproj = (ushort_t*)(ws + 8388608);              // [65536][1536] bf16
    ushort_t* emb   = (ushort_t*)(ws + 209715200);            // [65536][512] bf16
    ushort_t* ysb   = emb;  // reuse: emb dead after gemm2, ys written by scan

    dim3 tb(32, 8);
    transpose_to_bf16<<<dim3(16, 32), tb, 0, stream>>>(Wd, WdT, OBSD, HD);
    transpose_to_bf16<<<dim3(48, 16), tb, 0, stream>>>(Wi, WiT, HD, 1536);
    transpose_to_bf16<<<dim3(48, 16), tb, 0, stream>>>(Wh, WhT, HD, 1536);
    transpose_to_bf16<<<dim3(16, 16), tb, 0, stream>>>(Wc1, Wc1T, HD, FCD);
    init_value<<<256, 256, 0, stream>>>(out_v, bc2);

    // emb = relu(world_state @ Wd + bd)
    gemm64<OBSD, 0, true><<<dim3(MROWS / 64, HD / 64), 256, 0, stream>>>(
        world_state, WdT, bd, emb, HD, nullptr, nullptr);
    // LayerNorm in place
    ln_kernel<<<MROWS / 4, 256, 0, stream>>>(emb, lns, lnb);
    // xproj = emb @ Wi + bi
    gemm64<HD, 1, false><<<dim3(MROWS / 64, 1536 / 64), 256, 0, stream>>>(
        emb, WiT, bi, xproj, 1536, nullptr, nullptr);
    // sequential GRU scan (batch-independent row blocks)
    scan_kernel<<<32, 1024, 0, stream>>>(hidden, dones, WhT, bhn, xproj, ysb,
                                         out_h);
    // value = relu(ys @ Wc1 + bc1) @ Wc2 + bc2
    gemm64<HD, 2, false><<<dim3(MROWS / 64, FCD / 64), 256, 0, stream>>>(
        ysb, Wc1T, bc1, nullptr, 0, Wc2, out_v);
}